// Round 4
// baseline (195.536 us; speedup 1.0000x reference)
//
#include <hip/hip_runtime.h>

typedef __attribute__((ext_vector_type(8))) short short8;
typedef __attribute__((ext_vector_type(4))) float float4v;

__device__ __forceinline__ unsigned short f2bf(float f) {
    unsigned u = __float_as_uint(f);
    u = (u + 0x7FFFu + ((u >> 16) & 1u)) >> 16;
    return (unsigned short)u;
}

// direct global->LDS DMA, 16B/lane; LDS image = wave-uniform base + lane*16
#define GLOAD_LDS16(g, l) __builtin_amdgcn_global_load_lds( \
    (const __attribute__((address_space(1))) void*)(g),     \
    (__attribute__((address_space(3))) void*)(l), 16, 0, 0)

#define XSET 520    // z frag set: 512 data + 8 pad ushorts
#define XGRP 1040   // x group: 4ch x 64px fp32 (1024B) + 16B pad -> 2-way banks
#define XGRPF 260   // same in floats
#define CROW 66     // C staging row: 64 px + 2 pad floats (2-way banks)
#define XS_BYTES (64 * XGRP)        // 66560
#define ZS_BYTES (12 * XSET * 2)    // 12480

// ---------------------------------------------------------------------------
// Prepack: W1 [256x64], W2 [96x256] ([cin,cout]) -> bf16 MFMA A-frag order.
// A[m][k]: m = lane&15, k = (lane>>4)*8 + j.
// A1: ((mt*8 + ks)*64 + lane)*8 + j   (mt 0..3,  ks 0..7)
// A2: ((mt*3 + ks)*64 + lane)*8 + j   (mt 0..15, ks 0..2)
// ---------------------------------------------------------------------------
__global__ void prepack(const float* __restrict__ W1_0, const float* __restrict__ W2_0,
                        const float* __restrict__ W1_1, const float* __restrict__ W2_1,
                        const float* __restrict__ W1_2, const float* __restrict__ W2_2,
                        unsigned short* __restrict__ ws) {
    int e = blockIdx.x * 256 + threadIdx.x;
    if (e >= 3 * 40960) return;
    int l = e / 40960, r = e % 40960;
    const float* W1 = (l == 0) ? W1_0 : (l == 1) ? W1_1 : W1_2;
    const float* W2 = (l == 0) ? W2_0 : (l == 1) ? W2_1 : W2_2;
    unsigned short* base = ws + l * 40960;
    if (r < 16384) {
        int j = r & 7, lane = (r >> 3) & 63, fs = r >> 9;
        int mt = fs >> 3, ks = fs & 7;
        int k = ks * 32 + (lane >> 4) * 8 + j;
        int m = mt * 16 + (lane & 15);
        base[r] = f2bf(W1[k * 64 + m]);
    } else {
        int r2 = r - 16384;
        int j = r2 & 7, lane = (r2 >> 3) & 63, fs = r2 >> 9;
        int mt = fs / 3, ks = fs - mt * 3;
        int k = ks * 32 + (lane >> 4) * 8 + j;
        int m = mt * 16 + (lane & 15);
        base[16384 + r2] = f2bf(W2[k * 256 + m]);
    }
}

// ---------------------------------------------------------------------------
// Block = 256 thr (4 waves) = 64 px, all channels.
// Phase 1: x staged raw fp32 via global_load_lds dwordx4 (16 insts/wave,
//          zero VGPR cost -> 16KB in flight per wave).
// Stage 1: wave w = px group w; frag gather = 2-way-conflict ds_read_b32+cvt.
// Stage 2: wave w = out-ch 64w..64w+63, all 64 px; C -> LDS -> px-major
//          nontemporal dwordx4 stores (256B runs).
// ---------------------------------------------------------------------------
template<int HW>
__device__ __forceinline__ void level4(
    const float* __restrict__ x,           // this batch: [256][HW]
    const unsigned short* __restrict__ A1,
    const unsigned short* __restrict__ A2,
    const float* __restrict__ b1, const float* __restrict__ b2,
    float* __restrict__ o, int px0,
    unsigned char* __restrict__ xraw,      // XS_BYTES, aliased by C staging
    unsigned short* __restrict__ zs)       // ZS_BYTES
{
    const int t = (int)threadIdx.x;
    const int lane = t & 63, w = t >> 6;
    const int q = lane >> 4, n = lane & 15;

    // ---- phase 1: 16 direct-to-LDS 1KB loads per wave, back-to-back ----
    {
        const int ch_off = lane >> 4;           // 0..3 within group
        const int pxo = (lane & 15) * 4;        // 4 px per lane
#pragma unroll
        for (int it = 0; it < 16; ++it) {
            const int grp = w * 16 + it;        // 4-channel group 0..63
            const float* g = x + (size_t)(grp * 4 + ch_off) * HW + px0 + pxo;
            GLOAD_LDS16(g, xraw + grp * XGRP);
        }
    }
    __syncthreads();   // drains vmcnt -> x image complete

    // ---- stage 1: y[64][16] for px group w ----
    float4v acc1[4];
#pragma unroll
    for (int mt = 0; mt < 4; ++mt)
        acc1[mt] = *(const float4v*)(b1 + mt * 16 + q * 4);

    const float* xsf = (const float*)xraw;
    short8 xf[8];
#pragma unroll
    for (int ks = 0; ks < 8; ++ks) {
        unsigned short tmp[8];
#pragma unroll
        for (int j = 0; j < 8; ++j) {
            // ch = ks*32 + q*8 + j ; grp = ch>>2 ; within: (ch&3)*64 + px
            const int grp = ks * 8 + q * 2 + (j >> 2);
            tmp[j] = f2bf(xsf[grp * XGRPF + (j & 3) * 64 + w * 16 + n]);
        }
        short8 f;
#pragma unroll
        for (int j = 0; j < 8; ++j) f[j] = (short)tmp[j];
        xf[ks] = f;
    }

    const short8* A1f = (const short8*)A1;
#pragma unroll
    for (int ks = 0; ks < 8; ++ks)
#pragma unroll
        for (int mt = 0; mt < 4; ++mt)
            acc1[mt] = __builtin_amdgcn_mfma_f32_16x16x32_bf16(
                A1f[(mt * 8 + ks) * 64 + lane], xf[ks], acc1[mt], 0, 0, 0);

    // ---- z = [y, relu(y_hi)] -> shared frag-layout LDS (b64 packed) ----
    {
        unsigned short* zg = zs + w * 3 * XSET;
#pragma unroll
        for (int mt = 0; mt < 4; ++mt) {
            const int kb = mt * 16 + q * 4;
            unsigned long long pk =
                  (unsigned long long)f2bf(acc1[mt][0])
                | ((unsigned long long)f2bf(acc1[mt][1]) << 16)
                | ((unsigned long long)f2bf(acc1[mt][2]) << 32)
                | ((unsigned long long)f2bf(acc1[mt][3]) << 48);
            *(unsigned long long*)(zg + (kb >> 5) * XSET +
                (((kb >> 3) & 3) * 16 + n) * 8 + (kb & 7)) = pk;
            if (mt >= 2) {
                const int kr = kb + 32;
                unsigned long long pr =
                      (unsigned long long)f2bf(fmaxf(acc1[mt][0], 0.f))
                    | ((unsigned long long)f2bf(fmaxf(acc1[mt][1], 0.f)) << 16)
                    | ((unsigned long long)f2bf(fmaxf(acc1[mt][2], 0.f)) << 32)
                    | ((unsigned long long)f2bf(fmaxf(acc1[mt][3], 0.f)) << 48);
                *(unsigned long long*)(zg + (kr >> 5) * XSET +
                    (((kr >> 3) & 3) * 16 + n) * 8 + (kr & 7)) = pr;
            }
        }
    }
    __syncthreads();

    // ---- stage 2: out-ch 64w..64w+63, all 4 px groups ----
    float4v acc2[4][4];   // [mm][g]
#pragma unroll
    for (int mm = 0; mm < 4; ++mm) {
        float4v bb = *(const float4v*)(b2 + (w * 4 + mm) * 16 + q * 4);
#pragma unroll
        for (int g = 0; g < 4; ++g) acc2[mm][g] = bb;
    }

    const short8* A2f = (const short8*)A2;
#pragma unroll
    for (int g = 0; g < 4; ++g) {
        short8 zf[3];
#pragma unroll
        for (int ks = 0; ks < 3; ++ks)
            zf[ks] = *(const short8*)(zs + (g * 3 + ks) * XSET + lane * 8);
#pragma unroll
        for (int ks = 0; ks < 3; ++ks)
#pragma unroll
            for (int mm = 0; mm < 4; ++mm)
                acc2[mm][g] = __builtin_amdgcn_mfma_f32_16x16x32_bf16(
                    A2f[((w * 4 + mm) * 3 + ks) * 64 + lane], zf[ks], acc2[mm][g], 0, 0, 0);
    }

    // ---- store: C -> LDS (wave-private slot, aliases x region) -> global ----
    float* cw = (float*)xraw + w * 32 * CROW;
#pragma unroll
    for (int p = 0; p < 2; ++p) {
#pragma unroll
        for (int mp = 0; mp < 2; ++mp) {
            const int mm = p * 2 + mp;
#pragma unroll
            for (int g = 0; g < 4; ++g)
#pragma unroll
                for (int r = 0; r < 4; ++r)
                    cw[(mp * 16 + q * 4 + r) * CROW + g * 16 + n] = acc2[mm][g][r];
        }
        // wave-private slot: this wave's DS ops execute in order; no barrier
        const int chs = lane >> 4;
        const int pp = lane & 15;
        float* op = o + (size_t)(w * 64 + p * 32 + chs) * HW + px0 + 4 * pp;
#pragma unroll
        for (int i = 0; i < 8; ++i) {
            float4v v = *(const float4v*)(cw + (i * 4 + chs) * CROW + 4 * pp);
            __builtin_nontemporal_store(v, (float4v*)(op + (size_t)(i * 4) * HW));
        }
    }
}

__global__ __launch_bounds__(256, 2) void fused_v4(
    const float* __restrict__ x0, const float* __restrict__ x1, const float* __restrict__ x2,
    const float* __restrict__ b1_0, const float* __restrict__ b2_0,
    const float* __restrict__ b1_1, const float* __restrict__ b2_1,
    const float* __restrict__ b1_2, const float* __restrict__ b2_2,
    const unsigned short* __restrict__ wpk, float* __restrict__ out)
{
    __shared__ __align__(16) unsigned char smem[XS_BYTES + ZS_BYTES];  // 79040 B
    unsigned char*  xraw = smem;
    unsigned short* zs   = (unsigned short*)(smem + XS_BYTES);
    const int bi = (int)blockIdx.x;

    if (bi < 1024) {                        // level 0: 4 batches x 256 tiles
        int b = bi >> 8, px0 = (bi & 255) * 64;
        level4<16384>(x0 + (size_t)b * 256 * 16384, wpk, wpk + 16384, b1_0, b2_0,
                      out + (size_t)b * 256 * 16384, px0, xraw, zs);
    } else if (bi < 1280) {                 // level 1: 4 x 64 tiles
        int r = bi - 1024, b = r >> 6, px0 = (r & 63) * 64;
        level4<4096>(x1 + (size_t)b * 256 * 4096, wpk + 40960, wpk + 40960 + 16384,
                     b1_1, b2_1, out + 16777216 + (size_t)b * 256 * 4096, px0, xraw, zs);
    } else {                                // level 2: 4 x 16 tiles
        int r = bi - 1280, b = r >> 4, px0 = (r & 15) * 64;
        level4<1024>(x2 + (size_t)b * 256 * 1024, wpk + 81920, wpk + 81920 + 16384,
                     b1_2, b2_2, out + 20971520 + (size_t)b * 256 * 1024, px0, xraw, zs);
    }
}

extern "C" void kernel_launch(void* const* d_in, const int* in_sizes, int n_in,
                              void* d_out, int out_size, void* d_ws, size_t ws_size,
                              hipStream_t stream) {
    const float* x0   = (const float*)d_in[0];
    const float* x1   = (const float*)d_in[1];
    const float* x2   = (const float*)d_in[2];
    const float* W1_0 = (const float*)d_in[3];
    const float* b1_0 = (const float*)d_in[4];
    const float* W2_0 = (const float*)d_in[5];
    const float* b2_0 = (const float*)d_in[6];
    const float* W1_1 = (const float*)d_in[7];
    const float* b1_1 = (const float*)d_in[8];
    const float* W2_1 = (const float*)d_in[9];
    const float* b2_1 = (const float*)d_in[10];
    const float* W1_2 = (const float*)d_in[11];
    const float* b1_2 = (const float*)d_in[12];
    const float* W2_2 = (const float*)d_in[13];
    const float* b2_2 = (const float*)d_in[14];
    float* out = (float*)d_out;
    unsigned short* wpk = (unsigned short*)d_ws;   // needs 245760 B

    prepack<<<dim3(480), dim3(256), 0, stream>>>(W1_0, W2_0, W1_1, W2_1, W1_2, W2_2, wpk);
    fused_v4<<<dim3(1344), dim3(256), 0, stream>>>(
        x0, x1, x2, b1_0, b2_0, b1_1, b2_1, b1_2, b2_2, wpk, out);
}